// Round 1
// baseline (955.732 us; speedup 1.0000x reference)
//
#include <hip/hip_runtime.h>
#include <hip/hip_bf16.h>

#define D 256

typedef __attribute__((ext_vector_type(8))) short bf16x8;
typedef __attribute__((ext_vector_type(4))) float f32x4;

static __device__ __forceinline__ unsigned short f2bf(float f) {
  __hip_bfloat16 b = __float2bfloat16(f);
  return *reinterpret_cast<unsigned short*>(&b);
}

// ---------------- degree count ----------------
__global__ void deg_kernel(const int* __restrict__ row, int* __restrict__ deg, int E) {
  int e = blockIdx.x * blockDim.x + threadIdx.x;
  if (e < E) atomicAdd(&deg[row[e]], 1);
}

// ---------------- 3-kernel exclusive scan ----------------
__global__ void scan1(const int* __restrict__ deg, int* __restrict__ scanned,
                      int* __restrict__ partials, int n) {
  __shared__ int tmp[256];
  int i = blockIdx.x * 256 + threadIdx.x;
  int v = (i < n) ? deg[i] : 0;
  tmp[threadIdx.x] = v;
  __syncthreads();
  for (int off = 1; off < 256; off <<= 1) {
    int t = (threadIdx.x >= off) ? tmp[threadIdx.x - off] : 0;
    __syncthreads();
    tmp[threadIdx.x] += t;
    __syncthreads();
  }
  if (i < n) scanned[i] = tmp[threadIdx.x] - v;  // exclusive
  if (threadIdx.x == 255) partials[blockIdx.x] = tmp[255];
}

__global__ void scan2(int* __restrict__ partials, int nb) {
  __shared__ int tmp[512];
  int tid = threadIdx.x;
  int v = (tid < nb) ? partials[tid] : 0;
  tmp[tid] = v;
  __syncthreads();
  for (int off = 1; off < 512; off <<= 1) {
    int t = (tid >= off) ? tmp[tid - off] : 0;
    __syncthreads();
    tmp[tid] += t;
    __syncthreads();
  }
  if (tid < nb) partials[tid] = tmp[tid] - v;  // exclusive
}

__global__ void scan3(const int* __restrict__ scanned, const int* __restrict__ partials,
                      const int* __restrict__ deg, int* __restrict__ offsets,
                      int* __restrict__ cursor, float* __restrict__ dinv, int n, int E) {
  int i = blockIdx.x * 256 + threadIdx.x;
  if (i < n) {
    int o = scanned[i] + partials[blockIdx.x];
    offsets[i] = o;
    cursor[i] = o;
    int d = deg[i];
    dinv[i] = (d > 0) ? rsqrtf((float)d) : 0.0f;
    if (i == 0) offsets[n] = E;
  }
}

// ---------------- CSR fill ----------------
__global__ void fill_kernel(const int* __restrict__ row, const int* __restrict__ col,
                            int* __restrict__ cursor, int* __restrict__ csr_col, int E) {
  int e = blockIdx.x * blockDim.x + threadIdx.x;
  if (e < E) {
    int r = row[e];
    int pos = atomicAdd(&cursor[r], 1);
    csr_col[pos] = col[e];
  }
}

// ---------------- W transpose -> bf16 ----------------
__global__ void wt_kernel(const float* __restrict__ W, __hip_bfloat16* __restrict__ Wt) {
  int n = blockIdx.x, k = threadIdx.x;
  Wt[n * D + k] = __float2bfloat16(W[k * D + n]);
}

// ---------------- SpMM: one wave per node, float4 per lane ----------------
__global__ __launch_bounds__(256) void spmm_kernel(
    const int* __restrict__ offsets, const int* __restrict__ csr_col,
    const float* __restrict__ dinv, const float* __restrict__ x,
    __hip_bfloat16* __restrict__ h, int N) {
  int wave = threadIdx.x >> 6;
  int lane = threadIdx.x & 63;
  int i = blockIdx.x * 4 + wave;
  if (i >= N) return;
  int beg = offsets[i], end = offsets[i + 1];
  float di = dinv[i];
  const float4* x4 = reinterpret_cast<const float4*>(x);

  float4 acc = make_float4(0.f, 0.f, 0.f, 0.f);
  int e = beg;
  for (; e + 4 <= end; e += 4) {
    int c0 = csr_col[e], c1 = csr_col[e + 1], c2 = csr_col[e + 2], c3 = csr_col[e + 3];
    float w0 = di * dinv[c0], w1 = di * dinv[c1], w2 = di * dinv[c2], w3 = di * dinv[c3];
    float4 v0 = x4[(size_t)c0 * 64 + lane];
    float4 v1 = x4[(size_t)c1 * 64 + lane];
    float4 v2 = x4[(size_t)c2 * 64 + lane];
    float4 v3 = x4[(size_t)c3 * 64 + lane];
    acc.x += w0 * v0.x; acc.y += w0 * v0.y; acc.z += w0 * v0.z; acc.w += w0 * v0.w;
    acc.x += w1 * v1.x; acc.y += w1 * v1.y; acc.z += w1 * v1.z; acc.w += w1 * v1.w;
    acc.x += w2 * v2.x; acc.y += w2 * v2.y; acc.z += w2 * v2.z; acc.w += w2 * v2.w;
    acc.x += w3 * v3.x; acc.y += w3 * v3.y; acc.z += w3 * v3.z; acc.w += w3 * v3.w;
  }
  for (; e < end; ++e) {
    int c = csr_col[e];
    float w = di * dinv[c];
    float4 v = x4[(size_t)c * 64 + lane];
    acc.x += w * v.x; acc.y += w * v.y; acc.z += w * v.z; acc.w += w * v.w;
  }
  ushort4 o;
  o.x = f2bf(acc.x); o.y = f2bf(acc.y); o.z = f2bf(acc.z); o.w = f2bf(acc.w);
  *reinterpret_cast<ushort4*>(reinterpret_cast<unsigned short*>(h) + (size_t)i * D + lane * 4) = o;
}

// ---------------- GEMM: h[M,256] @ W[256,256] + b, leaky relu ----------------
// Wt is W transposed (Wt[n][k] = W[k][n]), bf16.
__global__ __launch_bounds__(256) void gemm_kernel(
    const __hip_bfloat16* __restrict__ h, const __hip_bfloat16* __restrict__ Wt,
    const float* __restrict__ bias, float* __restrict__ out, int M) {
  const int tid = threadIdx.x;
  const int wave = tid >> 6;
  const int lane = tid & 63;
  const int row0 = blockIdx.x * 64 + wave * 16;
  const int arow = row0 + (lane & 15);
  const int arow_c = (arow < M) ? arow : 0;
  const int kgrp = (lane >> 4) * 8;  // 0,8,16,24
  const int ncol = lane & 15;

  const short* hp = reinterpret_cast<const short*>(h);
  const short* wtp = reinterpret_cast<const short*>(Wt);

  bf16x8 a[8];
#pragma unroll
  for (int kk = 0; kk < 8; ++kk)
    a[kk] = *reinterpret_cast<const bf16x8*>(hp + (size_t)arow_c * D + kk * 32 + kgrp);

#pragma unroll
  for (int nt = 0; nt < 16; ++nt) {
    f32x4 acc = {0.f, 0.f, 0.f, 0.f};
#pragma unroll
    for (int kk = 0; kk < 8; ++kk) {
      bf16x8 bfrag = *reinterpret_cast<const bf16x8*>(wtp + (size_t)(nt * 16 + ncol) * D + kk * 32 + kgrp);
      acc = __builtin_amdgcn_mfma_f32_16x16x32_bf16(a[kk], bfrag, acc, 0, 0, 0);
    }
    int col = nt * 16 + ncol;
    float bv = bias[col];
#pragma unroll
    for (int r = 0; r < 4; ++r) {
      int row = row0 + (lane >> 4) * 4 + r;
      if (row < M) {
        float v = acc[r] + bv;
        out[(size_t)row * D + col] = (v >= 0.f) ? v : 0.2f * v;
      }
    }
  }
}

extern "C" void kernel_launch(void* const* d_in, const int* in_sizes, int n_in,
                              void* d_out, int out_size, void* d_ws, size_t ws_size,
                              hipStream_t stream) {
  const float* x = (const float*)d_in[0];
  const int* ei = (const int*)d_in[1];
  const float* W = (const float*)d_in[2];
  const float* b = (const float*)d_in[3];
  float* out = (float*)d_out;

  const int N = in_sizes[0] / D;
  const int E = in_sizes[1] / 2;
  const int* row = ei;
  const int* col = ei + E;

  char* ws = (char*)d_ws;
  size_t off = 0;
  auto alloc = [&](size_t bytes) -> void* {
    void* p = ws + off;
    off += (bytes + 255) & ~(size_t)255;
    return p;
  };
  int* deg = (int*)alloc((size_t)N * 4);
  int* scanned = (int*)alloc((size_t)N * 4);
  int* partials = (int*)alloc(512 * 4);
  int* offsets = (int*)alloc((size_t)(N + 1) * 4);
  int* cursor = (int*)alloc((size_t)N * 4);
  float* dinv = (float*)alloc((size_t)N * 4);
  int* csr_col = (int*)alloc((size_t)E * 4);
  __hip_bfloat16* h = (__hip_bfloat16*)alloc((size_t)N * D * 2);
  __hip_bfloat16* Wt = (__hip_bfloat16*)alloc((size_t)D * D * 2);

  hipMemsetAsync(deg, 0, (size_t)N * 4, stream);

  const int eb = (E + 255) / 256;
  const int nb = (N + 255) / 256;

  deg_kernel<<<eb, 256, 0, stream>>>(row, deg, E);
  scan1<<<nb, 256, 0, stream>>>(deg, scanned, partials, N);
  scan2<<<1, 512, 0, stream>>>(partials, nb);
  scan3<<<nb, 256, 0, stream>>>(scanned, partials, deg, offsets, cursor, dinv, N, E);
  fill_kernel<<<eb, 256, 0, stream>>>(row, col, cursor, csr_col, E);
  wt_kernel<<<D, D, 0, stream>>>(W, Wt);
  spmm_kernel<<<(N + 3) / 4, 256, 0, stream>>>(offsets, csr_col, dinv, x, h, N);
  gemm_kernel<<<(N + 63) / 64, 256, 0, stream>>>(h, Wt, b, out, N);
}

// Round 3
// 583.406 us; speedup vs baseline: 1.6382x; 1.6382x over previous
//
#include <hip/hip_runtime.h>
#include <hip/hip_bf16.h>

#define D 256

typedef __attribute__((ext_vector_type(8))) short bf16x8;
typedef __attribute__((ext_vector_type(4))) float f32x4;

static __device__ __forceinline__ unsigned int f2bf(float f) {
  __hip_bfloat16 b = __float2bfloat16(f);
  return (unsigned int)*reinterpret_cast<unsigned short*>(&b);
}
static __device__ __forceinline__ float u2f(unsigned int u) {
  return __uint_as_float(u);
}

static __device__ __forceinline__ void acc8(float* acc, uint4 v, float wt) {
  acc[0] += wt * u2f(v.x << 16);
  acc[1] += wt * u2f(v.x & 0xffff0000u);
  acc[2] += wt * u2f(v.y << 16);
  acc[3] += wt * u2f(v.y & 0xffff0000u);
  acc[4] += wt * u2f(v.z << 16);
  acc[5] += wt * u2f(v.z & 0xffff0000u);
  acc[6] += wt * u2f(v.w << 16);
  acc[7] += wt * u2f(v.w & 0xffff0000u);
}

// ---------------- degree count + per-edge rank ----------------
__global__ void deg_rank_kernel(const int* __restrict__ row, int* __restrict__ deg,
                                unsigned short* __restrict__ rank, int E) {
  int e = blockIdx.x * blockDim.x + threadIdx.x;
  if (e < E) rank[e] = (unsigned short)atomicAdd(&deg[row[e]], 1);
}

// ---------------- 3-kernel exclusive scan (in-place into offsets) ----------------
__global__ void scan1(const int* __restrict__ deg, int* __restrict__ offsets,
                      int* __restrict__ partials, int n) {
  __shared__ int tmp[256];
  int i = blockIdx.x * 256 + threadIdx.x;
  int v = (i < n) ? deg[i] : 0;
  tmp[threadIdx.x] = v;
  __syncthreads();
  for (int off = 1; off < 256; off <<= 1) {
    int t = (threadIdx.x >= off) ? tmp[threadIdx.x - off] : 0;
    __syncthreads();
    tmp[threadIdx.x] += t;
    __syncthreads();
  }
  if (i < n) offsets[i] = tmp[threadIdx.x] - v;  // exclusive within block
  if (threadIdx.x == 255) partials[blockIdx.x] = tmp[255];
}

__global__ void scan2(int* __restrict__ partials, int nb) {
  __shared__ int tmp[512];
  int tid = threadIdx.x;
  int v = (tid < nb) ? partials[tid] : 0;
  tmp[tid] = v;
  __syncthreads();
  for (int off = 1; off < 512; off <<= 1) {
    int t = (tid >= off) ? tmp[tid - off] : 0;
    __syncthreads();
    tmp[tid] += t;
    __syncthreads();
  }
  if (tid < nb) partials[tid] = tmp[tid] - v;  // exclusive
}

__global__ void scan3(int* __restrict__ offsets, const int* __restrict__ partials,
                      const int* __restrict__ deg, float* __restrict__ dinv, int n, int E) {
  int i = blockIdx.x * 256 + threadIdx.x;
  if (i < n) {
    offsets[i] += partials[blockIdx.x];
    int d = deg[i];
    dinv[i] = (d > 0) ? rsqrtf((float)d) : 0.0f;
    if (i == 0) offsets[n] = E;
  }
}

// ---------------- CSR fill (atomic-free) ----------------
__global__ void fill_kernel(const int* __restrict__ row, const int* __restrict__ col,
                            const int* __restrict__ offsets, const unsigned short* __restrict__ rank,
                            int* __restrict__ csr_col, int E) {
  int e = blockIdx.x * blockDim.x + threadIdx.x;
  if (e < E) {
    int pos = offsets[row[e]] + (int)rank[e];
    csr_col[pos] = col[e];
  }
}

// ---------------- x -> bf16 ----------------
__global__ void conv_kernel(const float* __restrict__ x, unsigned int* __restrict__ xb, int total8) {
  int idx = blockIdx.x * 256 + threadIdx.x;
  if (idx >= total8) return;
  const float4* x4 = reinterpret_cast<const float4*>(x);
  float4 a = x4[(size_t)idx * 2], b = x4[(size_t)idx * 2 + 1];
  uint4 o;
  o.x = f2bf(a.x) | (f2bf(a.y) << 16);
  o.y = f2bf(a.z) | (f2bf(a.w) << 16);
  o.z = f2bf(b.x) | (f2bf(b.y) << 16);
  o.w = f2bf(b.z) | (f2bf(b.w) << 16);
  reinterpret_cast<uint4*>(xb)[idx] = o;
}

// ---------------- W transpose -> bf16 ----------------
__global__ void wt_kernel(const float* __restrict__ W, __hip_bfloat16* __restrict__ Wt) {
  int n = blockIdx.x, k = threadIdx.x;
  Wt[n * D + k] = __float2bfloat16(W[k * D + n]);
}

// ---------------- SpMM (bf16 gather): one wave per node, 2 edges per wave-iter ----------------
__global__ __launch_bounds__(256) void spmm_bf16_kernel(
    const int* __restrict__ offsets, const int* __restrict__ csr_col,
    const float* __restrict__ dinv, const unsigned int* __restrict__ xb,
    unsigned short* __restrict__ h, int N) {
  int wave = threadIdx.x >> 6;
  int lane = threadIdx.x & 63;
  int i = blockIdx.x * 4 + wave;
  if (i >= N) return;
  int half = lane >> 5;  // which edge of the pair
  int l = lane & 31;     // 8-feature chunk
  int beg = offsets[i], end = offsets[i + 1];
  float di = dinv[i];
  const uint4* xb4 = reinterpret_cast<const uint4*>(xb);  // 32 uint4 per row

  float acc[8];
#pragma unroll
  for (int j = 0; j < 8; ++j) acc[j] = 0.f;

  int e = beg + half;
  for (; e + 6 < end; e += 8) {
    int c0 = csr_col[e], c1 = csr_col[e + 2], c2 = csr_col[e + 4], c3 = csr_col[e + 6];
    float w0 = di * dinv[c0], w1 = di * dinv[c1], w2 = di * dinv[c2], w3 = di * dinv[c3];
    uint4 v0 = xb4[(size_t)c0 * 32 + l];
    uint4 v1 = xb4[(size_t)c1 * 32 + l];
    uint4 v2 = xb4[(size_t)c2 * 32 + l];
    uint4 v3 = xb4[(size_t)c3 * 32 + l];
    acc8(acc, v0, w0);
    acc8(acc, v1, w1);
    acc8(acc, v2, w2);
    acc8(acc, v3, w3);
  }
  for (; e < end; e += 2) {
    int c = csr_col[e];
    float w = di * dinv[c];
    uint4 v = xb4[(size_t)c * 32 + l];
    acc8(acc, v, w);
  }

  // combine the two half-wave partials (same feature chunk, different edges)
#pragma unroll
  for (int j = 0; j < 8; ++j) acc[j] += __shfl(acc[j], lane ^ 32, 64);

  if (half == 0) {
    uint4 o;
    o.x = f2bf(acc[0]) | (f2bf(acc[1]) << 16);
    o.y = f2bf(acc[2]) | (f2bf(acc[3]) << 16);
    o.z = f2bf(acc[4]) | (f2bf(acc[5]) << 16);
    o.w = f2bf(acc[6]) | (f2bf(acc[7]) << 16);
    reinterpret_cast<uint4*>(h)[(size_t)i * 32 + l] = o;
  }
}

// ---------------- SpMM fallback (f32 gather) ----------------
__global__ __launch_bounds__(256) void spmm_f32_kernel(
    const int* __restrict__ offsets, const int* __restrict__ csr_col,
    const float* __restrict__ dinv, const float* __restrict__ x,
    unsigned short* __restrict__ h, int N) {
  int wave = threadIdx.x >> 6;
  int lane = threadIdx.x & 63;
  int i = blockIdx.x * 4 + wave;
  if (i >= N) return;
  int beg = offsets[i], end = offsets[i + 1];
  float di = dinv[i];
  const float4* x4 = reinterpret_cast<const float4*>(x);

  float4 acc = make_float4(0.f, 0.f, 0.f, 0.f);
  int e = beg;
  for (; e + 4 <= end; e += 4) {
    int c0 = csr_col[e], c1 = csr_col[e + 1], c2 = csr_col[e + 2], c3 = csr_col[e + 3];
    float w0 = di * dinv[c0], w1 = di * dinv[c1], w2 = di * dinv[c2], w3 = di * dinv[c3];
    float4 v0 = x4[(size_t)c0 * 64 + lane];
    float4 v1 = x4[(size_t)c1 * 64 + lane];
    float4 v2 = x4[(size_t)c2 * 64 + lane];
    float4 v3 = x4[(size_t)c3 * 64 + lane];
    acc.x += w0 * v0.x; acc.y += w0 * v0.y; acc.z += w0 * v0.z; acc.w += w0 * v0.w;
    acc.x += w1 * v1.x; acc.y += w1 * v1.y; acc.z += w1 * v1.z; acc.w += w1 * v1.w;
    acc.x += w2 * v2.x; acc.y += w2 * v2.y; acc.z += w2 * v2.z; acc.w += w2 * v2.w;
    acc.x += w3 * v3.x; acc.y += w3 * v3.y; acc.z += w3 * v3.z; acc.w += w3 * v3.w;
  }
  for (; e < end; ++e) {
    int c = csr_col[e];
    float w = di * dinv[c];
    float4 v = x4[(size_t)c * 64 + lane];
    acc.x += w * v.x; acc.y += w * v.y; acc.z += w * v.z; acc.w += w * v.w;
  }
  ushort4 o;
  o.x = (unsigned short)f2bf(acc.x);
  o.y = (unsigned short)f2bf(acc.y);
  o.z = (unsigned short)f2bf(acc.z);
  o.w = (unsigned short)f2bf(acc.w);
  *reinterpret_cast<ushort4*>(h + (size_t)i * D + lane * 4) = o;
}

// ---------------- GEMM: h[M,256] @ W[256,256] + b, leaky relu ----------------
__global__ __launch_bounds__(256) void gemm_kernel(
    const __hip_bfloat16* __restrict__ h, const __hip_bfloat16* __restrict__ Wt,
    const float* __restrict__ bias, float* __restrict__ out, int M) {
  const int tid = threadIdx.x;
  const int wave = tid >> 6;
  const int lane = tid & 63;
  const int row0 = blockIdx.x * 64 + wave * 16;
  const int arow = row0 + (lane & 15);
  const int arow_c = (arow < M) ? arow : 0;
  const int kgrp = (lane >> 4) * 8;  // 0,8,16,24
  const int ncol = lane & 15;

  const short* hp = reinterpret_cast<const short*>(h);
  const short* wtp = reinterpret_cast<const short*>(Wt);

  bf16x8 a[8];
#pragma unroll
  for (int kk = 0; kk < 8; ++kk)
    a[kk] = *reinterpret_cast<const bf16x8*>(hp + (size_t)arow_c * D + kk * 32 + kgrp);

#pragma unroll
  for (int nt = 0; nt < 16; ++nt) {
    f32x4 acc = {0.f, 0.f, 0.f, 0.f};
#pragma unroll
    for (int kk = 0; kk < 8; ++kk) {
      bf16x8 bfrag = *reinterpret_cast<const bf16x8*>(wtp + (size_t)(nt * 16 + ncol) * D + kk * 32 + kgrp);
      acc = __builtin_amdgcn_mfma_f32_16x16x32_bf16(a[kk], bfrag, acc, 0, 0, 0);
    }
    int col = nt * 16 + ncol;
    float bv = bias[col];
#pragma unroll
    for (int r = 0; r < 4; ++r) {
      int row = row0 + (lane >> 4) * 4 + r;
      if (row < M) {
        float v = acc[r] + bv;
        out[(size_t)row * D + col] = (v >= 0.f) ? v : 0.2f * v;
      }
    }
  }
}

extern "C" void kernel_launch(void* const* d_in, const int* in_sizes, int n_in,
                              void* d_out, int out_size, void* d_ws, size_t ws_size,
                              hipStream_t stream) {
  const float* x = (const float*)d_in[0];
  const int* ei = (const int*)d_in[1];
  const float* W = (const float*)d_in[2];
  const float* b = (const float*)d_in[3];
  float* out = (float*)d_out;

  const int N = in_sizes[0] / D;
  const int E = in_sizes[1] / 2;
  const int* row = ei;
  const int* col = ei + E;

  char* ws = (char*)d_ws;
  size_t off = 0;
  auto alloc = [&](size_t bytes) -> void* {
    void* p = ws + off;
    off += (bytes + 255) & ~(size_t)255;
    return p;
  };
  int* deg = (int*)alloc((size_t)N * 4);
  int* offsets = (int*)alloc((size_t)(N + 1) * 4);
  int* partials = (int*)alloc(512 * 4);
  float* dinv = (float*)alloc((size_t)N * 4);
  int* csr_col = (int*)alloc((size_t)E * 4);
  unsigned short* h = (unsigned short*)alloc((size_t)N * D * 2);
  __hip_bfloat16* Wt = (__hip_bfloat16*)alloc((size_t)D * D * 2);
  // union region: rank (read until fill) then xb (written after fill, same stream => ordered)
  size_t union_off = off;
  unsigned short* rank = (unsigned short*)alloc((size_t)E * 2);
  size_t need_fallback = off;
  size_t need_bf16 = union_off + (((size_t)N * D * 2 + 255) & ~(size_t)255);
  if (need_bf16 < need_fallback) need_bf16 = need_fallback;
  const bool use_bf16 = (need_bf16 <= ws_size);
  unsigned int* xb = (unsigned int*)(ws + union_off);

  (void)hipMemsetAsync(deg, 0, (size_t)N * 4, stream);

  const int eb = (E + 255) / 256;
  const int nb = (N + 255) / 256;

  deg_rank_kernel<<<eb, 256, 0, stream>>>(row, deg, rank, E);
  scan1<<<nb, 256, 0, stream>>>(deg, offsets, partials, N);
  scan2<<<1, 512, 0, stream>>>(partials, nb);
  scan3<<<nb, 256, 0, stream>>>(offsets, partials, deg, dinv, N, E);
  fill_kernel<<<eb, 256, 0, stream>>>(row, col, offsets, rank, csr_col, E);
  wt_kernel<<<D, D, 0, stream>>>(W, Wt);
  if (use_bf16) {
    const int total8 = N * D / 8;
    conv_kernel<<<(total8 + 255) / 256, 256, 0, stream>>>(x, xb, total8);
    spmm_bf16_kernel<<<(N + 3) / 4, 256, 0, stream>>>(offsets, csr_col, dinv, xb, h, N);
  } else {
    spmm_f32_kernel<<<(N + 3) / 4, 256, 0, stream>>>(offsets, csr_col, dinv, x, h, N);
  }
  gemm_kernel<<<(N + 63) / 64, 256, 0, stream>>>((const __hip_bfloat16*)h, Wt, b, out, N);
}

// Round 4
// 566.613 us; speedup vs baseline: 1.6867x; 1.0296x over previous
//
#include <hip/hip_runtime.h>
#include <hip/hip_bf16.h>

#define D 256

typedef __attribute__((ext_vector_type(8))) short bf16x8;
typedef __attribute__((ext_vector_type(4))) float f32x4;

static __device__ __forceinline__ unsigned int f2bf(float f) {
  __hip_bfloat16 b = __float2bfloat16(f);
  return (unsigned int)*reinterpret_cast<unsigned short*>(&b);
}
static __device__ __forceinline__ float u2f(unsigned int u) {
  return __uint_as_float(u);
}

static __device__ __forceinline__ void acc8_add(float* acc, uint4 v) {
  acc[0] += u2f(v.x << 16);
  acc[1] += u2f(v.x & 0xffff0000u);
  acc[2] += u2f(v.y << 16);
  acc[3] += u2f(v.y & 0xffff0000u);
  acc[4] += u2f(v.z << 16);
  acc[5] += u2f(v.z & 0xffff0000u);
  acc[6] += u2f(v.w << 16);
  acc[7] += u2f(v.w & 0xffff0000u);
}

// ---------------- degree count + per-edge rank ----------------
__global__ void deg_rank_kernel(const int* __restrict__ row, int* __restrict__ deg,
                                unsigned short* __restrict__ rank, int E) {
  int e = blockIdx.x * blockDim.x + threadIdx.x;
  if (e < E) rank[e] = (unsigned short)atomicAdd(&deg[row[e]], 1);
}

// ---------------- 3-kernel exclusive scan (in-place into offsets) ----------------
__global__ void scan1(const int* __restrict__ deg, int* __restrict__ offsets,
                      int* __restrict__ partials, int n) {
  __shared__ int tmp[256];
  int i = blockIdx.x * 256 + threadIdx.x;
  int v = (i < n) ? deg[i] : 0;
  tmp[threadIdx.x] = v;
  __syncthreads();
  for (int off = 1; off < 256; off <<= 1) {
    int t = (threadIdx.x >= off) ? tmp[threadIdx.x - off] : 0;
    __syncthreads();
    tmp[threadIdx.x] += t;
    __syncthreads();
  }
  if (i < n) offsets[i] = tmp[threadIdx.x] - v;  // exclusive within block
  if (threadIdx.x == 255) partials[blockIdx.x] = tmp[255];
}

__global__ void scan2(int* __restrict__ partials, int nb) {
  __shared__ int tmp[512];
  int tid = threadIdx.x;
  int v = (tid < nb) ? partials[tid] : 0;
  tmp[tid] = v;
  __syncthreads();
  for (int off = 1; off < 512; off <<= 1) {
    int t = (tid >= off) ? tmp[tid - off] : 0;
    __syncthreads();
    tmp[tid] += t;
    __syncthreads();
  }
  if (tid < nb) partials[tid] = tmp[tid] - v;  // exclusive
}

__global__ void scan3(int* __restrict__ offsets, const int* __restrict__ partials,
                      const int* __restrict__ deg, float* __restrict__ dinv, int n, int E) {
  int i = blockIdx.x * 256 + threadIdx.x;
  if (i < n) {
    offsets[i] += partials[blockIdx.x];
    int d = deg[i];
    dinv[i] = (d > 0) ? rsqrtf((float)d) : 0.0f;
    if (i == 0) offsets[n] = E;
  }
}

// ---------------- CSR fill (atomic-free) ----------------
__global__ void fill_kernel(const int* __restrict__ row, const int* __restrict__ col,
                            const int* __restrict__ offsets, const unsigned short* __restrict__ rank,
                            int* __restrict__ csr_col, int E) {
  int e = blockIdx.x * blockDim.x + threadIdx.x;
  if (e < E) {
    int pos = offsets[row[e]] + (int)rank[e];
    csr_col[pos] = col[e];
  }
}

// ---------------- x * dinv -> bf16, split into two 128-feature stripes ----------------
__global__ void conv_kernel(const float* __restrict__ x, const float* __restrict__ dinv,
                            uint4* __restrict__ xb0, uint4* __restrict__ xb1, int total8) {
  int idx = blockIdx.x * 256 + threadIdx.x;
  if (idx >= total8) return;
  int j = idx >> 5;   // node
  int k8 = idx & 31;  // which 8-feature chunk within the node
  float s = dinv[j];
  const float4* x4 = reinterpret_cast<const float4*>(x);
  float4 a = x4[(size_t)idx * 2], b = x4[(size_t)idx * 2 + 1];
  uint4 o;
  o.x = f2bf(a.x * s) | (f2bf(a.y * s) << 16);
  o.y = f2bf(a.z * s) | (f2bf(a.w * s) << 16);
  o.z = f2bf(b.x * s) | (f2bf(b.y * s) << 16);
  o.w = f2bf(b.z * s) | (f2bf(b.w * s) << 16);
  uint4* dst = (k8 < 16) ? xb0 : xb1;
  dst[(size_t)j * 16 + (k8 & 15)] = o;
}

// ---------------- W transpose -> bf16 ----------------
__global__ void wt_kernel(const float* __restrict__ W, __hip_bfloat16* __restrict__ Wt) {
  int n = blockIdx.x, k = threadIdx.x;
  Wt[n * D + k] = __float2bfloat16(W[k * D + n]);
}

// ---------------- SpMM half-stripe: one wave per node, 4 edges per wave-instr ----------------
// xb: [N][16] uint4 (128 bf16 features, pre-scaled by dinv[src]).
// h: [N][32] uint4; this pass writes h[i][hoff .. hoff+15].
__global__ __launch_bounds__(256) void spmm_half_kernel(
    const int* __restrict__ offsets, const int* __restrict__ csr_col,
    const float* __restrict__ dinv, const uint4* __restrict__ xb,
    uint4* __restrict__ h, int N, int hoff) {
  int wave = threadIdx.x >> 6;
  int lane = threadIdx.x & 63;
  int i = blockIdx.x * 4 + wave;
  if (i >= N) return;
  int g = lane >> 4;  // edge group 0..3
  int l = lane & 15;  // 8-feature chunk within stripe
  int beg = offsets[i], end = offsets[i + 1];

  float acc[8];
#pragma unroll
  for (int j = 0; j < 8; ++j) acc[j] = 0.f;

  int e = beg + g;
  // 16 edges per iteration (4 per group), 4 gathers in flight
  for (; e + 12 < end; e += 16) {
    int c0 = csr_col[e], c1 = csr_col[e + 4], c2 = csr_col[e + 8], c3 = csr_col[e + 12];
    uint4 v0 = xb[(size_t)c0 * 16 + l];
    uint4 v1 = xb[(size_t)c1 * 16 + l];
    uint4 v2 = xb[(size_t)c2 * 16 + l];
    uint4 v3 = xb[(size_t)c3 * 16 + l];
    acc8_add(acc, v0);
    acc8_add(acc, v1);
    acc8_add(acc, v2);
    acc8_add(acc, v3);
  }
  for (; e < end; e += 4) {
    int c = csr_col[e];
    uint4 v = xb[(size_t)c * 16 + l];
    acc8_add(acc, v);
  }

  // combine the 4 edge-group partials
#pragma unroll
  for (int j = 0; j < 8; ++j) {
    acc[j] += __shfl(acc[j], lane ^ 16, 64);
    acc[j] += __shfl(acc[j], lane ^ 32, 64);
  }

  if (g == 0) {
    float di = dinv[i];
    uint4 o;
    o.x = f2bf(acc[0] * di) | (f2bf(acc[1] * di) << 16);
    o.y = f2bf(acc[2] * di) | (f2bf(acc[3] * di) << 16);
    o.z = f2bf(acc[4] * di) | (f2bf(acc[5] * di) << 16);
    o.w = f2bf(acc[6] * di) | (f2bf(acc[7] * di) << 16);
    h[(size_t)i * 32 + hoff + l] = o;
  }
}

// ---------------- SpMM fallback (f32 gather, full row) ----------------
__global__ __launch_bounds__(256) void spmm_f32_kernel(
    const int* __restrict__ offsets, const int* __restrict__ csr_col,
    const float* __restrict__ dinv, const float* __restrict__ x,
    unsigned short* __restrict__ h, int N) {
  int wave = threadIdx.x >> 6;
  int lane = threadIdx.x & 63;
  int i = blockIdx.x * 4 + wave;
  if (i >= N) return;
  int beg = offsets[i], end = offsets[i + 1];
  float di = dinv[i];
  const float4* x4 = reinterpret_cast<const float4*>(x);

  float4 acc = make_float4(0.f, 0.f, 0.f, 0.f);
  for (int e = beg; e < end; ++e) {
    int c = csr_col[e];
    float w = di * dinv[c];
    float4 v = x4[(size_t)c * 64 + lane];
    acc.x += w * v.x; acc.y += w * v.y; acc.z += w * v.z; acc.w += w * v.w;
  }
  ushort4 o;
  o.x = (unsigned short)f2bf(acc.x);
  o.y = (unsigned short)f2bf(acc.y);
  o.z = (unsigned short)f2bf(acc.z);
  o.w = (unsigned short)f2bf(acc.w);
  *reinterpret_cast<ushort4*>(h + (size_t)i * D + lane * 4) = o;
}

// ---------------- GEMM: h[M,256] @ W[256,256] + b, leaky relu ----------------
__global__ __launch_bounds__(256) void gemm_kernel(
    const __hip_bfloat16* __restrict__ h, const __hip_bfloat16* __restrict__ Wt,
    const float* __restrict__ bias, float* __restrict__ out, int M) {
  const int tid = threadIdx.x;
  const int wave = tid >> 6;
  const int lane = tid & 63;
  const int row0 = blockIdx.x * 64 + wave * 16;
  const int arow = row0 + (lane & 15);
  const int arow_c = (arow < M) ? arow : 0;
  const int kgrp = (lane >> 4) * 8;  // 0,8,16,24
  const int ncol = lane & 15;

  const short* hp = reinterpret_cast<const short*>(h);
  const short* wtp = reinterpret_cast<const short*>(Wt);

  bf16x8 a[8];
#pragma unroll
  for (int kk = 0; kk < 8; ++kk)
    a[kk] = *reinterpret_cast<const bf16x8*>(hp + (size_t)arow_c * D + kk * 32 + kgrp);

#pragma unroll
  for (int nt = 0; nt < 16; ++nt) {
    f32x4 acc = {0.f, 0.f, 0.f, 0.f};
#pragma unroll
    for (int kk = 0; kk < 8; ++kk) {
      bf16x8 bfrag = *reinterpret_cast<const bf16x8*>(wtp + (size_t)(nt * 16 + ncol) * D + kk * 32 + kgrp);
      acc = __builtin_amdgcn_mfma_f32_16x16x32_bf16(a[kk], bfrag, acc, 0, 0, 0);
    }
    int col = nt * 16 + ncol;
    float bv = bias[col];
#pragma unroll
    for (int r = 0; r < 4; ++r) {
      int row = row0 + (lane >> 4) * 4 + r;
      if (row < M) {
        float v = acc[r] + bv;
        out[(size_t)row * D + col] = (v >= 0.f) ? v : 0.2f * v;
      }
    }
  }
}

extern "C" void kernel_launch(void* const* d_in, const int* in_sizes, int n_in,
                              void* d_out, int out_size, void* d_ws, size_t ws_size,
                              hipStream_t stream) {
  const float* x = (const float*)d_in[0];
  const int* ei = (const int*)d_in[1];
  const float* W = (const float*)d_in[2];
  const float* b = (const float*)d_in[3];
  float* out = (float*)d_out;

  const int N = in_sizes[0] / D;
  const int E = in_sizes[1] / 2;
  const int* row = ei;
  const int* col = ei + E;

  char* ws = (char*)d_ws;
  size_t off = 0;
  auto alloc = [&](size_t bytes) -> void* {
    void* p = ws + off;
    off += (bytes + 255) & ~(size_t)255;
    return p;
  };
  int* deg = (int*)alloc((size_t)N * 4);
  int* offsets = (int*)alloc((size_t)(N + 1) * 4);
  int* partials = (int*)alloc(512 * 4);
  float* dinv = (float*)alloc((size_t)N * 4);
  int* csr_col = (int*)alloc((size_t)E * 4);
  unsigned short* h = (unsigned short*)alloc((size_t)N * D * 2);
  __hip_bfloat16* Wt = (__hip_bfloat16*)alloc((size_t)D * D * 2);
  // union region: rank (read until fill) then xb0/xb1 (written after fill, same stream => ordered)
  size_t union_off = off;
  unsigned short* rank = (unsigned short*)alloc((size_t)E * 2);
  size_t need_fallback = off;
  size_t xb_bytes = (size_t)N * D * 2;  // both stripes combined
  size_t need_bf16 = union_off + ((xb_bytes + 255) & ~(size_t)255);
  if (need_bf16 < need_fallback) need_bf16 = need_fallback;
  const bool use_bf16 = (need_bf16 <= ws_size);
  uint4* xb0 = (uint4*)(ws + union_off);
  uint4* xb1 = xb0 + (size_t)N * 16;

  (void)hipMemsetAsync(deg, 0, (size_t)N * 4, stream);

  const int eb = (E + 255) / 256;
  const int nb = (N + 255) / 256;

  deg_rank_kernel<<<eb, 256, 0, stream>>>(row, deg, rank, E);
  scan1<<<nb, 256, 0, stream>>>(deg, offsets, partials, N);
  scan2<<<1, 512, 0, stream>>>(partials, nb);
  scan3<<<nb, 256, 0, stream>>>(offsets, partials, deg, dinv, N, E);
  fill_kernel<<<eb, 256, 0, stream>>>(row, col, offsets, rank, csr_col, E);
  wt_kernel<<<D, D, 0, stream>>>(W, Wt);
  if (use_bf16) {
    const int total8 = N * D / 8;
    conv_kernel<<<(total8 + 255) / 256, 256, 0, stream>>>(x, dinv, xb0, xb1, total8);
    spmm_half_kernel<<<(N + 3) / 4, 256, 0, stream>>>(offsets, csr_col, dinv, xb0, (uint4*)h, N, 0);
    spmm_half_kernel<<<(N + 3) / 4, 256, 0, stream>>>(offsets, csr_col, dinv, xb1, (uint4*)h, N, 16);
  } else {
    spmm_f32_kernel<<<(N + 3) / 4, 256, 0, stream>>>(offsets, csr_col, dinv, x, h, N);
  }
  gemm_kernel<<<(N + 63) / 64, 256, 0, stream>>>((const __hip_bfloat16*)h, Wt, b, out, N);
}

// Round 5
// 513.595 us; speedup vs baseline: 1.8609x; 1.1032x over previous
//
#include <hip/hip_runtime.h>
#include <hip/hip_bf16.h>

#define D 256
#define CH 8192  // edges per count/scatter block

typedef __attribute__((ext_vector_type(8))) short bf16x8;
typedef __attribute__((ext_vector_type(4))) float f32x4;

static __device__ __forceinline__ unsigned int f2bf(float f) {
  __hip_bfloat16 b = __float2bfloat16(f);
  return (unsigned int)*reinterpret_cast<unsigned short*>(&b);
}
static __device__ __forceinline__ float u2f(unsigned int u) {
  return __uint_as_float(u);
}

static __device__ __forceinline__ void acc8w(float* acc, uint4 v, float wt) {
  acc[0] += wt * u2f(v.x << 16);
  acc[1] += wt * u2f(v.x & 0xffff0000u);
  acc[2] += wt * u2f(v.y << 16);
  acc[3] += wt * u2f(v.y & 0xffff0000u);
  acc[4] += wt * u2f(v.z << 16);
  acc[5] += wt * u2f(v.z & 0xffff0000u);
  acc[6] += wt * u2f(v.w << 16);
  acc[7] += wt * u2f(v.w & 0xffff0000u);
}

// ============ FAST BUILD: deterministic counting-sort CSR ============

// K1 fused: [0,nblk) row-bucket count | [nblk,nblk+convb) x->bf16 stripes | [+,+D) W^T
__global__ __launch_bounds__(256) void fused_prep_kernel(
    const int* __restrict__ row, const float* __restrict__ x, const float* __restrict__ W,
    uint4* __restrict__ xb0, uint4* __restrict__ xb1, __hip_bfloat16* __restrict__ Wt,
    int* __restrict__ counts, int E, int NB, int nblk, int total8, int convb) {
  __shared__ int hist[2048];
  int bid = blockIdx.x, tid = threadIdx.x;
  if (bid < nblk) {
    for (int t = tid; t < NB; t += 256) hist[t] = 0;
    __syncthreads();
    int e0 = bid * CH, e1 = min(E, e0 + CH);
    for (int e = e0 + tid; e < e1; e += 256) atomicAdd(&hist[row[e] >> 6], 1);
    __syncthreads();
    for (int t = tid; t < NB; t += 256) counts[(size_t)bid * NB + t] = hist[t];
  } else if (bid < nblk + convb) {
    int idx = (bid - nblk) * 256 + tid;
    if (idx < total8) {
      int j = idx >> 5, k8 = idx & 31;
      const float4* x4 = reinterpret_cast<const float4*>(x);
      float4 a = x4[(size_t)idx * 2], bb = x4[(size_t)idx * 2 + 1];
      uint4 o;
      o.x = f2bf(a.x) | (f2bf(a.y) << 16);
      o.y = f2bf(a.z) | (f2bf(a.w) << 16);
      o.z = f2bf(bb.x) | (f2bf(bb.y) << 16);
      o.w = f2bf(bb.z) | (f2bf(bb.w) << 16);
      uint4* dst = (k8 < 16) ? xb0 : xb1;
      dst[(size_t)j * 16 + (k8 & 15)] = o;
    }
  } else {
    int n = bid - nblk - convb;  // 0..D-1
    Wt[n * D + tid] = __float2bfloat16(W[tid * D + n]);
  }
}

// K2a: per-bucket exclusive scan over blocks; counts[blk][t] -> base-within-bucket
__global__ void colscan_kernel(int* counts, int* total, int NB, int nblk) {
  int t = blockIdx.x * 256 + threadIdx.x;
  if (t >= NB) return;
  int run = 0;
#pragma unroll 4
  for (int blk = 0; blk < nblk; ++blk) {
    size_t idx = (size_t)blk * NB + t;
    int c = counts[idx];
    counts[idx] = run;
    run += c;
  }
  total[t] = run;
}

// K2b: single-block exclusive scan of bucket totals -> bucket_base[NB+1]
__global__ void bucket_scan_kernel(const int* __restrict__ total, int* __restrict__ bucket_base,
                                   int NB) {
  __shared__ int a[2048], b2[2048];
  int t = threadIdx.x;  // 1024 threads
  for (int k = 0; k < 2; ++k) {
    int i = t + k * 1024;
    a[i] = (i < NB) ? total[i] : 0;
  }
  __syncthreads();
  int* cur = a;
  int* nxt = b2;
  for (int off = 1; off < 2048; off <<= 1) {
    for (int k = 0; k < 2; ++k) {
      int i = t + k * 1024;
      int v = cur[i];
      if (i >= off) v += cur[i - off];
      nxt[i] = v;
    }
    __syncthreads();
    int* tmp = cur; cur = nxt; nxt = tmp;
  }
  if (t == 0) bucket_base[0] = 0;
  for (int k = 0; k < 2; ++k) {
    int i = t + k * 1024;
    if (i < NB) bucket_base[i + 1] = cur[i];
  }
}

// K3: stable scatter into bucket order; pack (row&63)<<17 | col
__global__ __launch_bounds__(256) void scatter_kernel(
    const int* __restrict__ row, const int* __restrict__ col, const int* __restrict__ counts,
    const int* __restrict__ bucket_base, unsigned int* __restrict__ sorted, int E, int NB) {
  __shared__ int base[2048];
  __shared__ int cur[2048];
  int bid = blockIdx.x, tid = threadIdx.x;
  for (int t = tid; t < NB; t += 256) {
    base[t] = bucket_base[t] + counts[(size_t)bid * NB + t];
    cur[t] = 0;
  }
  __syncthreads();
  int e0 = bid * CH, e1 = min(E, e0 + CH);
  for (int e = e0 + tid; e < e1; e += 256) {
    int r = row[e], c = col[e];
    int b = r >> 6;
    int p = base[b] + atomicAdd(&cur[b], 1);
    sorted[p] = ((unsigned int)(r & 63) << 17) | (unsigned int)c;
  }
}

// K4: per-bucket CSR with (row, col>>13) sub-grouping -> offsets, dinv, csr_col
__global__ __launch_bounds__(256) void bucket_csr_kernel(
    const unsigned int* __restrict__ sorted, const int* __restrict__ bucket_base,
    int* __restrict__ offsets, float* __restrict__ dinv, int* __restrict__ csr_col,
    int N, int E, int NB, int ncb) {
  __shared__ int cnt[1024];
  int b = blockIdx.x, tid = threadIdx.x;
  int lo = bucket_base[b], hi = bucket_base[b + 1];
  int slots = 64 * ncb;
  for (int t = tid; t < slots; t += 256) cnt[t] = 0;
  __syncthreads();
  for (int e = lo + tid; e < hi; e += 256) {
    unsigned int v = sorted[e];
    atomicAdd(&cnt[(v >> 17) * ncb + ((v & 0x1FFFFu) >> 13)], 1);
  }
  __syncthreads();
  if (tid == 0) {
    int run = 0;
    for (int i2 = 0; i2 < slots; ++i2) {
      int t2 = cnt[i2];
      cnt[i2] = run;
      run += t2;
    }
  }
  __syncthreads();
  if (tid < 64) {
    int gr = b * 64 + tid;
    if (gr < N) {
      int start = cnt[tid * ncb];
      int nxt = (tid == 63) ? (hi - lo) : cnt[(tid + 1) * ncb];
      int dg = nxt - start;
      offsets[gr] = lo + start;
      dinv[gr] = (dg > 0) ? rsqrtf((float)dg) : 0.f;
    }
  }
  if (b == NB - 1 && tid == 0) offsets[N] = E;
  __syncthreads();
  for (int e = lo + tid; e < hi; e += 256) {
    unsigned int v = sorted[e];
    int p = lo + atomicAdd(&cnt[(v >> 17) * ncb + ((v & 0x1FFFFu) >> 13)], 1);
    csr_col[p] = (int)(v & 0x1FFFFu);
  }
}

// ============ SpMM (bf16 stripes, per-edge dinv weight) ============
__global__ __launch_bounds__(256) void spmm_half_kernel(
    const int* __restrict__ offsets, const int* __restrict__ csr_col,
    const float* __restrict__ dinv, const uint4* __restrict__ xb,
    uint4* __restrict__ h, int N, int hoff) {
  int wave = threadIdx.x >> 6;
  int lane = threadIdx.x & 63;
  int i = blockIdx.x * 4 + wave;
  if (i >= N) return;
  int g = lane >> 4;  // edge group 0..3
  int l = lane & 15;  // 8-feature chunk within stripe
  int beg = offsets[i], end = offsets[i + 1];

  float acc[8];
#pragma unroll
  for (int j = 0; j < 8; ++j) acc[j] = 0.f;

  int e = beg + g;
  for (; e + 12 < end; e += 16) {
    int c0 = csr_col[e], c1 = csr_col[e + 4], c2 = csr_col[e + 8], c3 = csr_col[e + 12];
    float w0 = dinv[c0], w1 = dinv[c1], w2 = dinv[c2], w3 = dinv[c3];
    uint4 v0 = xb[(size_t)c0 * 16 + l];
    uint4 v1 = xb[(size_t)c1 * 16 + l];
    uint4 v2 = xb[(size_t)c2 * 16 + l];
    uint4 v3 = xb[(size_t)c3 * 16 + l];
    acc8w(acc, v0, w0);
    acc8w(acc, v1, w1);
    acc8w(acc, v2, w2);
    acc8w(acc, v3, w3);
  }
  for (; e < end; e += 4) {
    int c = csr_col[e];
    float w = dinv[c];
    uint4 v = xb[(size_t)c * 16 + l];
    acc8w(acc, v, w);
  }

#pragma unroll
  for (int j = 0; j < 8; ++j) {
    acc[j] += __shfl(acc[j], lane ^ 16, 64);
    acc[j] += __shfl(acc[j], lane ^ 32, 64);
  }

  if (g == 0) {
    float di = dinv[i];
    uint4 o;
    o.x = f2bf(acc[0] * di) | (f2bf(acc[1] * di) << 16);
    o.y = f2bf(acc[2] * di) | (f2bf(acc[3] * di) << 16);
    o.z = f2bf(acc[4] * di) | (f2bf(acc[5] * di) << 16);
    o.w = f2bf(acc[6] * di) | (f2bf(acc[7] * di) << 16);
    h[(size_t)i * 32 + hoff + l] = o;
  }
}

// ============ FALLBACK build (atomic, from round 4) ============
__global__ void deg_rank_kernel(const int* __restrict__ row, int* __restrict__ deg,
                                unsigned short* __restrict__ rank, int E) {
  int e = blockIdx.x * blockDim.x + threadIdx.x;
  if (e < E) rank[e] = (unsigned short)atomicAdd(&deg[row[e]], 1);
}
__global__ void scan1(const int* __restrict__ deg, int* __restrict__ offsets,
                      int* __restrict__ partials, int n) {
  __shared__ int tmp[256];
  int i = blockIdx.x * 256 + threadIdx.x;
  int v = (i < n) ? deg[i] : 0;
  tmp[threadIdx.x] = v;
  __syncthreads();
  for (int off = 1; off < 256; off <<= 1) {
    int t = (threadIdx.x >= off) ? tmp[threadIdx.x - off] : 0;
    __syncthreads();
    tmp[threadIdx.x] += t;
    __syncthreads();
  }
  if (i < n) offsets[i] = tmp[threadIdx.x] - v;
  if (threadIdx.x == 255) partials[blockIdx.x] = tmp[255];
}
__global__ void scan2(int* __restrict__ partials, int nb) {
  __shared__ int tmp[512];
  int tid = threadIdx.x;
  int v = (tid < nb) ? partials[tid] : 0;
  tmp[tid] = v;
  __syncthreads();
  for (int off = 1; off < 512; off <<= 1) {
    int t = (tid >= off) ? tmp[tid - off] : 0;
    __syncthreads();
    tmp[tid] += t;
    __syncthreads();
  }
  if (tid < nb) partials[tid] = tmp[tid] - v;
}
__global__ void scan3(int* __restrict__ offsets, const int* __restrict__ partials,
                      const int* __restrict__ deg, float* __restrict__ dinv, int n, int E) {
  int i = blockIdx.x * 256 + threadIdx.x;
  if (i < n) {
    offsets[i] += partials[blockIdx.x];
    int d = deg[i];
    dinv[i] = (d > 0) ? rsqrtf((float)d) : 0.0f;
    if (i == 0) offsets[n] = E;
  }
}
__global__ void fill_kernel(const int* __restrict__ row, const int* __restrict__ col,
                            const int* __restrict__ offsets, const unsigned short* __restrict__ rank,
                            int* __restrict__ csr_col, int E) {
  int e = blockIdx.x * blockDim.x + threadIdx.x;
  if (e < E) {
    int pos = offsets[row[e]] + (int)rank[e];
    csr_col[pos] = col[e];
  }
}
__global__ void wt_kernel(const float* __restrict__ W, __hip_bfloat16* __restrict__ Wt) {
  int n = blockIdx.x, k = threadIdx.x;
  Wt[n * D + k] = __float2bfloat16(W[k * D + n]);
}
__global__ __launch_bounds__(256) void spmm_f32_kernel(
    const int* __restrict__ offsets, const int* __restrict__ csr_col,
    const float* __restrict__ dinv, const float* __restrict__ x,
    unsigned short* __restrict__ h, int N) {
  int wave = threadIdx.x >> 6;
  int lane = threadIdx.x & 63;
  int i = blockIdx.x * 4 + wave;
  if (i >= N) return;
  int beg = offsets[i], end = offsets[i + 1];
  float di = dinv[i];
  const float4* x4 = reinterpret_cast<const float4*>(x);
  float4 acc = make_float4(0.f, 0.f, 0.f, 0.f);
  for (int e = beg; e < end; ++e) {
    int c = csr_col[e];
    float w = di * dinv[c];
    float4 v = x4[(size_t)c * 64 + lane];
    acc.x += w * v.x; acc.y += w * v.y; acc.z += w * v.z; acc.w += w * v.w;
  }
  ushort4 o;
  o.x = (unsigned short)f2bf(acc.x);
  o.y = (unsigned short)f2bf(acc.y);
  o.z = (unsigned short)f2bf(acc.z);
  o.w = (unsigned short)f2bf(acc.w);
  *reinterpret_cast<ushort4*>(h + (size_t)i * D + lane * 4) = o;
}

// ============ GEMM ============
__global__ __launch_bounds__(256) void gemm_kernel(
    const __hip_bfloat16* __restrict__ h, const __hip_bfloat16* __restrict__ Wt,
    const float* __restrict__ bias, float* __restrict__ out, int M) {
  const int tid = threadIdx.x;
  const int wave = tid >> 6;
  const int lane = tid & 63;
  const int row0 = blockIdx.x * 64 + wave * 16;
  const int arow = row0 + (lane & 15);
  const int arow_c = (arow < M) ? arow : 0;
  const int kgrp = (lane >> 4) * 8;
  const int ncol = lane & 15;

  const short* hp = reinterpret_cast<const short*>(h);
  const short* wtp = reinterpret_cast<const short*>(Wt);

  bf16x8 a[8];
#pragma unroll
  for (int kk = 0; kk < 8; ++kk)
    a[kk] = *reinterpret_cast<const bf16x8*>(hp + (size_t)arow_c * D + kk * 32 + kgrp);

#pragma unroll
  for (int nt = 0; nt < 16; ++nt) {
    f32x4 acc = {0.f, 0.f, 0.f, 0.f};
#pragma unroll
    for (int kk = 0; kk < 8; ++kk) {
      bf16x8 bfrag = *reinterpret_cast<const bf16x8*>(wtp + (size_t)(nt * 16 + ncol) * D + kk * 32 + kgrp);
      acc = __builtin_amdgcn_mfma_f32_16x16x32_bf16(a[kk], bfrag, acc, 0, 0, 0);
    }
    int col = nt * 16 + ncol;
    float bv = bias[col];
#pragma unroll
    for (int r = 0; r < 4; ++r) {
      int row = row0 + (lane >> 4) * 4 + r;
      if (row < M) {
        float v = acc[r] + bv;
        out[(size_t)row * D + col] = (v >= 0.f) ? v : 0.2f * v;
      }
    }
  }
}

extern "C" void kernel_launch(void* const* d_in, const int* in_sizes, int n_in,
                              void* d_out, int out_size, void* d_ws, size_t ws_size,
                              hipStream_t stream) {
  const float* x = (const float*)d_in[0];
  const int* ei = (const int*)d_in[1];
  const float* W = (const float*)d_in[2];
  const float* b = (const float*)d_in[3];
  float* out = (float*)d_out;

  const int N = in_sizes[0] / D;
  const int E = in_sizes[1] / 2;
  const int* row = ei;
  const int* col = ei + E;

  char* ws = (char*)d_ws;
  size_t off = 0;
  auto alloc = [&](size_t bytes) -> void* {
    void* p = ws + off;
    off += (bytes + 255) & ~(size_t)255;
    return p;
  };
  auto align256 = [](size_t v) { return (v + 255) & ~(size_t)255; };

  int* offsets = (int*)alloc((size_t)(N + 1) * 4);
  float* dinv = (float*)alloc((size_t)N * 4);
  int* csr_col = (int*)alloc((size_t)E * 4);
  char* hreg = (char*)alloc((size_t)N * D * 2);  // h; early phase hosts sorted/counts/bases
  __hip_bfloat16* Wt = (__hip_bfloat16*)alloc((size_t)D * D * 2);
  size_t tail_off = off;  // union: xb (fast) | deg+partials+rank (fallback)

  const int NB = (N + 63) >> 6;
  const int ncb = (N + 8191) >> 13;
  const int nblk = (E + CH - 1) / CH;
  const int total8 = N * D / 8;
  const int convb = (total8 + 255) / 256;

  // sub-layout inside hreg
  size_t s_sorted = 0;
  size_t s_counts = s_sorted + align256((size_t)E * 4);
  size_t s_base = s_counts + align256((size_t)nblk * NB * 4);
  size_t s_total = s_base + align256((size_t)(NB + 1) * 4);
  size_t h_need = s_total + (size_t)NB * 4;

  size_t fast_need = tail_off + align256((size_t)N * D * 2);
  bool use_fast = (N <= 131072) && (NB <= 2048) && (ncb <= 16) &&
                  (h_need <= (size_t)N * D * 2) && (fast_need <= ws_size);

  unsigned short* h = (unsigned short*)hreg;

  if (use_fast) {
    unsigned int* sorted = (unsigned int*)(hreg + s_sorted);
    int* counts = (int*)(hreg + s_counts);
    int* bucket_base = (int*)(hreg + s_base);
    int* total = (int*)(hreg + s_total);
    uint4* xb0 = (uint4*)(ws + tail_off);
    uint4* xb1 = xb0 + (size_t)N * 16;

    fused_prep_kernel<<<nblk + convb + D, 256, 0, stream>>>(
        row, x, W, xb0, xb1, Wt, counts, E, NB, nblk, total8, convb);
    colscan_kernel<<<(NB + 255) / 256, 256, 0, stream>>>(counts, total, NB, nblk);
    bucket_scan_kernel<<<1, 1024, 0, stream>>>(total, bucket_base, NB);
    scatter_kernel<<<nblk, 256, 0, stream>>>(row, col, counts, bucket_base, sorted, E, NB);
    bucket_csr_kernel<<<NB, 256, 0, stream>>>(sorted, bucket_base, offsets, dinv, csr_col,
                                              N, E, NB, ncb);
    spmm_half_kernel<<<(N + 3) / 4, 256, 0, stream>>>(offsets, csr_col, dinv, xb0, (uint4*)h, N, 0);
    spmm_half_kernel<<<(N + 3) / 4, 256, 0, stream>>>(offsets, csr_col, dinv, xb1, (uint4*)h, N, 16);
  } else {
    // fallback: atomic build + f32 SpMM
    size_t foff = tail_off;
    int* deg = (int*)(ws + foff); foff += align256((size_t)N * 4);
    int* partials = (int*)(ws + foff); foff += align256(512 * 4);
    unsigned short* rank = (unsigned short*)(ws + foff); foff += align256((size_t)E * 2);
    (void)hipMemsetAsync(deg, 0, (size_t)N * 4, stream);
    const int eb = (E + 255) / 256;
    const int nb = (N + 255) / 256;
    deg_rank_kernel<<<eb, 256, 0, stream>>>(row, deg, rank, E);
    scan1<<<nb, 256, 0, stream>>>(deg, offsets, partials, N);
    scan2<<<1, 512, 0, stream>>>(partials, nb);
    scan3<<<nb, 256, 0, stream>>>(offsets, partials, deg, dinv, N, E);
    fill_kernel<<<eb, 256, 0, stream>>>(row, col, offsets, rank, csr_col, E);
    wt_kernel<<<D, D, 0, stream>>>(W, Wt);
    spmm_f32_kernel<<<(N + 3) / 4, 256, 0, stream>>>(offsets, csr_col, dinv, x, h, N);
  }
  gemm_kernel<<<(N + 63) / 64, 256, 0, stream>>>((const __hip_bfloat16*)h, Wt, b, out, N);
}